// Round 1
// baseline (330.512 us; speedup 1.0000x reference)
//
#include <hip/hip_runtime.h>
#include <math.h>

#define DIM 128
#define S_STRIPES 4

// ---------------- utility ----------------
__global__ void k_zero(int* __restrict__ p, long long n) {
  long long i = (long long)blockIdx.x * blockDim.x + threadIdx.x;
  long long stride = (long long)gridDim.x * blockDim.x;
  for (; i < n; i += stride) p[i] = 0;
}

// mark referenced sub nodes + striped histogram of obj
__global__ void k_mark_hist(const int* __restrict__ edges, int n_edge,
                            int* __restrict__ mark, int* __restrict__ countS) {
  int tid = blockIdx.x * blockDim.x + threadIdx.x;
  int stride = gridDim.x * blockDim.x;
  for (int e = tid; e < n_edge; e += stride) {
    int sub = edges[e * 6 + 4];
    int obj = edges[e * 6 + 5];
    mark[sub] = 1;                       // benign race (same value)
    int s = (e >> 6) & (S_STRIPES - 1);  // must match scatter's stripe fn
    atomicAdd(&countS[obj * S_STRIPES + s], 1);
  }
}

// OUT[r] = IN[r] @ W (128x128), one wave per row, optional row mask
__global__ void k_proj(const float* __restrict__ IN, const float* __restrict__ W,
                       float* __restrict__ OUT, int rows, const int* __restrict__ mask) {
  int wave = (blockIdx.x * blockDim.x + threadIdx.x) >> 6;
  int lane = threadIdx.x & 63;
  int nwaves = (gridDim.x * blockDim.x) >> 6;
  const float2* Wp = (const float2*)W;
  for (int r = wave; r < rows; r += nwaves) {
    if (mask && !mask[r]) continue;
    const float* in = IN + (long long)r * DIM;
    float2 acc = {0.f, 0.f};
#pragma unroll 4
    for (int k = 0; k < DIM; ++k) {
      float a = in[k];
      float2 w = Wp[k * 64 + lane];
      acc.x += a * w.x;
      acc.y += a * w.y;
    }
    ((float2*)(OUT + (long long)r * DIM))[lane] = acc;
  }
}

// C4[c] = kg[c>>1]@Wkg[0:128] + kg[c&1]@Wkg[128:256] + b   (c = hb*2+tb)
__global__ void k_c4(const float* __restrict__ kg, const float* __restrict__ Wkg,
                     const float* __restrict__ b, float* __restrict__ C4) {
  int j = threadIdx.x;  // 0..127
  for (int c = 0; c < 4; ++c) {
    int hb = c >> 1, tb = c & 1;
    float s = b[j];
    for (int k = 0; k < DIM; ++k) {
      s += kg[hb * DIM + k] * Wkg[k * DIM + j];
      s += kg[tb * DIM + k] * Wkg[(DIM + k) * DIM + j];
    }
    C4[c * DIM + j] = s;
  }
}

// ---------------- scan (3-phase, 1024 elems/block) ----------------
__global__ void k_scan_a(const int* __restrict__ in, int* __restrict__ out,
                         int* __restrict__ bsum, int L) {
  __shared__ int sh[256];
  int t = threadIdx.x;
  int base = blockIdx.x * 1024 + t * 4;
  int v[4];
  int sum = 0;
#pragma unroll
  for (int i = 0; i < 4; i++) { v[i] = (base + i < L) ? in[base + i] : 0; sum += v[i]; }
  sh[t] = sum;
  __syncthreads();
  for (int d = 1; d < 256; d <<= 1) {
    int x = (t >= d) ? sh[t - d] : 0;
    __syncthreads();
    sh[t] += x;
    __syncthreads();
  }
  int run = (t > 0) ? sh[t - 1] : 0;
  if (t == 255) bsum[blockIdx.x] = sh[255];
#pragma unroll
  for (int i = 0; i < 4; i++) {
    if (base + i < L) out[base + i] = run;
    run += v[i];
  }
}

__global__ void k_scan_b(int* __restrict__ bsum, int nb) {
  __shared__ int sh[512];
  int t = threadIdx.x;
  int v = (t < nb) ? bsum[t] : 0;
  sh[t] = v;
  __syncthreads();
  for (int d = 1; d < 512; d <<= 1) {
    int x = (t >= d) ? sh[t - d] : 0;
    __syncthreads();
    sh[t] += x;
    __syncthreads();
  }
  if (t < nb) bsum[t] = (t > 0) ? sh[t - 1] : 0;
}

__global__ void k_scan_c(int* __restrict__ out, int* __restrict__ cursor,
                         const int* __restrict__ bsum, int L, int n_edge) {
  int f = blockIdx.x * blockDim.x + threadIdx.x;
  if (f == 0) out[L] = n_edge;
  if (f < L) {
    int v = out[f] + bsum[f >> 10];
    out[f] = v;
    cursor[f] = v;
  }
}

// ---------------- per-edge alpha + scatter (16 lanes/edge) ----------------
__global__ void k_scatter_alpha(const int* __restrict__ edges, int n_edge,
                                const float* __restrict__ P1, const float* __restrict__ P2,
                                const float* __restrict__ C4, const float* __restrict__ w_alpha,
                                const float* __restrict__ w_alpha_b,
                                const int* __restrict__ left_ptr,
                                int* __restrict__ cursor, int* __restrict__ perm,
                                float* __restrict__ alpha) {
  int tid = blockIdx.x * blockDim.x + threadIdx.x;
  int group = tid >> 4;
  int ngroups = (gridDim.x * blockDim.x) >> 4;
  int l = threadIdx.x & 15;
  int left = left_ptr[0];
  float wb = w_alpha_b[0];
  for (int e = group; e < n_edge; e += ngroups) {
    int head = edges[e * 6 + 1];
    int rel  = edges[e * 6 + 2];
    int tail = edges[e * 6 + 3];
    int sub  = edges[e * 6 + 4];
    int obj  = edges[e * 6 + 5];
    int c = ((head >= left) ? 2 : 0) | ((tail >= left) ? 1 : 0);
    const float4* p1 = (const float4*)(P1 + (long long)sub * DIM);
    const float4* p2 = (const float4*)(P2 + (long long)rel * DIM);
    const float4* pc = (const float4*)(C4 + c * DIM);
    const float4* wa = (const float4*)w_alpha;
    float s = 0.f;
#pragma unroll
    for (int q = 0; q < 2; ++q) {
      int idx = l * 2 + q;  // float4 index 0..31
      float4 a = p1[idx], b2 = p2[idx], cc = pc[idx], w4 = wa[idx];
      s += fmaxf(a.x + b2.x + cc.x, 0.f) * w4.x;
      s += fmaxf(a.y + b2.y + cc.y, 0.f) * w4.y;
      s += fmaxf(a.z + b2.z + cc.z, 0.f) * w4.z;
      s += fmaxf(a.w + b2.w + cc.w, 0.f) * w4.w;
    }
    s += __shfl_xor(s, 1);
    s += __shfl_xor(s, 2);
    s += __shfl_xor(s, 4);
    s += __shfl_xor(s, 8);
    if (l == 0) {
      float z = s + wb;
      alpha[e] = 1.f / (1.f + expf(-z));
      int stripe = (e >> 6) & (S_STRIPES - 1);  // same fn as histogram
      int pos = atomicAdd(&cursor[obj * S_STRIPES + stripe], 1);
      perm[pos] = e;
    }
  }
}

// ---------------- segmented aggregation: block per node, 4 waves ----------------
__global__ void k_agg(const int* __restrict__ edges, const float* __restrict__ hidden,
                      const float* __restrict__ rela, const float* __restrict__ alpha,
                      const int* __restrict__ perm, const int* __restrict__ off,
                      float* __restrict__ agg) {
  int n = blockIdx.x;
  int w = threadIdx.x >> 6;
  int lane = threadIdx.x & 63;
  int start = off[n * S_STRIPES];
  int end = off[(n + 1) * S_STRIPES];
  float2 acc = {0.f, 0.f};
  for (int i = start + w; i < end; i += 4) {
    int e = perm[i];
    int sub = edges[e * 6 + 4];
    int rel = edges[e * 6 + 2];
    float al = alpha[e];
    float2 h = ((const float2*)(hidden + (long long)sub * DIM))[lane];
    float2 r = ((const float2*)(rela + (long long)rel * DIM))[lane];
    acc.x += al * (h.x + r.x);
    acc.y += al * (h.y + r.y);
  }
  __shared__ float2 sh[4][64];
  sh[w][lane] = acc;
  __syncthreads();
  if (w == 0) {
    float2 a0 = sh[0][lane], a1 = sh[1][lane], a2 = sh[2][lane], a3 = sh[3][lane];
    float2 o;
    o.x = a0.x + a1.x + a2.x + a3.x;
    o.y = a0.y + a1.y + a2.y + a3.y;
    ((float2*)(agg + (long long)n * DIM))[lane] = o;
  }
}

// ---------------- final projection, adaptive zero fast-path ----------------
__global__ void k_out(const float* __restrict__ agg, const float* __restrict__ Wh,
                      const int* __restrict__ off, int n_node, float* __restrict__ out) {
  int wave = (blockIdx.x * blockDim.x + threadIdx.x) >> 6;
  int lane = threadIdx.x & 63;
  int nwaves = (gridDim.x * blockDim.x) >> 6;
  const float2* Wp = (const float2*)Wh;
  for (int r = wave; r < n_node; r += nwaves) {
    float2* o = (float2*)(out + (long long)r * DIM);
    if (off[r * S_STRIPES] == off[(r + 1) * S_STRIPES]) {
      o[lane] = make_float2(0.f, 0.f);
      continue;
    }
    const float* in = agg + (long long)r * DIM;
    float2 acc = {0.f, 0.f};
#pragma unroll 4
    for (int k = 0; k < DIM; ++k) {
      float a = in[k];
      float2 wv = Wp[k * 64 + lane];
      acc.x += a * wv.x;
      acc.y += a * wv.y;
    }
    o[lane] = acc;
  }
}

extern "C" void kernel_launch(void* const* d_in, const int* in_sizes, int n_in,
                              void* d_out, int out_size, void* d_ws, size_t ws_size,
                              hipStream_t stream) {
  const float* hidden    = (const float*)d_in[0];
  const int*   edges     = (const int*)d_in[1];
  const float* kg_table  = (const float*)d_in[2];
  const float* rela      = (const float*)d_in[3];
  const float* Ws        = (const float*)d_in[4];
  const float* Wr        = (const float*)d_in[5];
  const float* Wkg_w     = (const float*)d_in[6];
  const float* Wkg_b     = (const float*)d_in[7];
  const float* w_alpha   = (const float*)d_in[8];
  const float* w_alpha_b = (const float*)d_in[9];
  const float* Wh        = (const float*)d_in[10];
  const int*   left_ptr  = (const int*)d_in[12];

  int n_node = out_size / DIM;
  int n_edge = in_sizes[1] / 6;
  int n_rel  = in_sizes[3] / DIM;
  int L  = S_STRIPES * n_node;
  int nb = (L + 1023) / 1024;

  char* ws = (char*)d_ws;
  size_t o = 0;
  auto alloc = [&](size_t b) { size_t r = o; o += (b + 255) & ~(size_t)255; return r; };
  float* P1     = (float*)(ws + alloc((size_t)n_node * DIM * 4));  // reused as agg
  float* P2     = (float*)(ws + alloc((size_t)n_rel * DIM * 4));
  float* C4     = (float*)(ws + alloc(4 * DIM * 4));
  int*   countS = (int*)(ws + alloc((size_t)(S_STRIPES + 1) * n_node * 4));
  int*   mark   = countS + (size_t)S_STRIPES * n_node;
  int*   off    = (int*)(ws + alloc((size_t)(L + 1) * 4));
  int*   cursor = (int*)(ws + alloc((size_t)L * 4));
  int*   bsum   = (int*)(ws + alloc((size_t)nb * 4));
  int*   perm   = (int*)(ws + alloc((size_t)n_edge * 4));
  float* alpha  = (float*)(ws + alloc((size_t)n_edge * 4));
  float* agg    = P1;  // P1 dead after k_scatter_alpha
  float* out    = (float*)d_out;

  // 1. zero count+mark
  k_zero<<<2048, 256, 0, stream>>>(countS, (long long)(S_STRIPES + 1) * n_node);
  // 2. mark subs + striped obj histogram
  k_mark_hist<<<(n_edge + 255) / 256, 256, 0, stream>>>(edges, n_edge, mark, countS);
  // 3. projections
  k_proj<<<2048, 256, 0, stream>>>(hidden, Ws, P1, n_node, mark);
  k_proj<<<(n_rel * 64 + 255) / 256, 256, 0, stream>>>(rela, Wr, P2, n_rel, (const int*)nullptr);
  k_c4<<<1, 128, 0, stream>>>(kg_table, Wkg_w, Wkg_b, C4);
  // 4. scan counts -> offsets (+ cursor copy)
  k_scan_a<<<nb, 256, 0, stream>>>(countS, off, bsum, L);
  k_scan_b<<<1, 512, 0, stream>>>(bsum, nb);
  k_scan_c<<<(L + 255) / 256, 256, 0, stream>>>(off, cursor, bsum, L, n_edge);
  // 5. per-edge alpha + counting-sort scatter
  k_scatter_alpha<<<(n_edge * 16 + 255) / 256, 256, 0, stream>>>(
      edges, n_edge, P1, P2, C4, w_alpha, w_alpha_b, left_ptr, cursor, perm, alpha);
  // 6. segmented sum (block per node)
  k_agg<<<n_node, 256, 0, stream>>>(edges, hidden, rela, alpha, perm, off, agg);
  // 7. out = agg @ Wh with zero fast-path
  k_out<<<(n_node * 64 + 255) / 256, 256, 0, stream>>>(agg, Wh, off, n_node, out);
}

// Round 2
// 245.686 us; speedup vs baseline: 1.3453x; 1.3453x over previous
//
#include <hip/hip_runtime.h>
#include <math.h>

#define DIM  128
#define KCAP 1024   // dense cap for sub/obj indices
#define CW   2048   // AB row width: [0,KCAP)=sub coeffs, [KCAP,2*KCAP)=rel coeffs

// ---------------- build SRC = [hidden[0:mr]; pad; rela[0:nr2]; pad] ----------------
__global__ void k_src(const float* __restrict__ hidden, const float* __restrict__ rela,
                      float* __restrict__ SRC, int mr, int nr2) {
  int i = blockIdx.x * blockDim.x + threadIdx.x;  // float4 index
  int total = CW * (DIM / 4);
  int stride = gridDim.x * blockDim.x;
  const float4* H = (const float4*)hidden;
  const float4* R = (const float4*)rela;
  float4* S = (float4*)SRC;
  for (; i < total; i += stride) {
    int row = i >> 5;  // DIM/4 = 32 float4 per row
    float4 v = make_float4(0.f, 0.f, 0.f, 0.f);
    if (row < mr) v = H[i];
    else if (row >= KCAP && (row - KCAP) < nr2) v = R[i - KCAP * 32];
    S[i] = v;
  }
}

// ---------------- OUT[r] = IN[r] @ W (128x128), one wave per row ----------------
__global__ void k_proj(const float* __restrict__ IN, const float* __restrict__ W,
                       float* __restrict__ OUT, int rows) {
  int wave = (blockIdx.x * blockDim.x + threadIdx.x) >> 6;
  int lane = threadIdx.x & 63;
  int nwaves = (gridDim.x * blockDim.x) >> 6;
  const float2* Wp = (const float2*)W;
  for (int r = wave; r < rows; r += nwaves) {
    const float* in = IN + (long long)r * DIM;
    float2 acc = {0.f, 0.f};
#pragma unroll 4
    for (int k = 0; k < DIM; ++k) {
      float a = in[k];
      float2 w = Wp[k * 64 + lane];
      acc.x += a * w.x;
      acc.y += a * w.y;
    }
    ((float2*)(OUT + (long long)r * DIM))[lane] = acc;
  }
}

// ---------------- C4[c] = kg[c>>1]@Wkg[0:128] + kg[c&1]@Wkg[128:256] + b ----------------
__global__ void k_c4(const float* __restrict__ kg, const float* __restrict__ Wkg,
                     const float* __restrict__ b, float* __restrict__ C4) {
  int j = threadIdx.x;  // 0..127
  for (int c = 0; c < 4; ++c) {
    int hb = c >> 1, tb = c & 1;
    float s = b[j];
    for (int k = 0; k < DIM; ++k) {
      s += kg[hb * DIM + k] * Wkg[k * DIM + j];
      s += kg[tb * DIM + k] * Wkg[(DIM + k) * DIM + j];
    }
    C4[c * DIM + j] = s;
  }
}

// ---------------- per-edge alpha + coefficient scatter (16 lanes/edge) ----------------
__global__ void k_edge(const int* __restrict__ edges, int n_edge,
                       const float* __restrict__ P1, const float* __restrict__ P2,
                       const float* __restrict__ C4, const float* __restrict__ w_alpha,
                       const float* __restrict__ w_alpha_b, const int* __restrict__ left_ptr,
                       float* __restrict__ AB, int* __restrict__ fb_list,
                       int* __restrict__ fb_count, int mr, int nr2) {
  int tid = blockIdx.x * blockDim.x + threadIdx.x;
  int group = tid >> 4;
  int ngroups = (gridDim.x * blockDim.x) >> 4;
  int l = threadIdx.x & 15;
  int base = (threadIdx.x & 63) & ~15;  // wave-lane of group start
  int left = left_ptr[0];
  float wb = w_alpha_b[0];
  for (int e = group; e < n_edge; e += ngroups) {
    int v = (l < 6) ? edges[e * 6 + l] : 0;
    int head = __shfl(v, base + 1);
    int rel  = __shfl(v, base + 2);
    int tail = __shfl(v, base + 3);
    int sub  = __shfl(v, base + 4);
    int obj  = __shfl(v, base + 5);
    if (sub >= mr || obj >= mr || rel >= nr2) {
      if (l == 0) {
        int pos = atomicAdd(fb_count, 1);
        fb_list[pos] = e;
      }
      continue;
    }
    int c = ((head >= left) ? 2 : 0) | ((tail >= left) ? 1 : 0);
    const float4* p1 = (const float4*)(P1 + (long long)sub * DIM);
    const float4* p2 = (const float4*)(P2 + (long long)rel * DIM);
    const float4* pc = (const float4*)(C4 + c * DIM);
    const float4* wa = (const float4*)w_alpha;
    float s = 0.f;
#pragma unroll
    for (int q = 0; q < 2; ++q) {
      int idx = l * 2 + q;  // float4 index 0..31
      float4 a = p1[idx], b2 = p2[idx], cc = pc[idx], w4 = wa[idx];
      s += fmaxf(a.x + b2.x + cc.x, 0.f) * w4.x;
      s += fmaxf(a.y + b2.y + cc.y, 0.f) * w4.y;
      s += fmaxf(a.z + b2.z + cc.z, 0.f) * w4.z;
      s += fmaxf(a.w + b2.w + cc.w, 0.f) * w4.w;
    }
    s += __shfl_xor(s, 1);
    s += __shfl_xor(s, 2);
    s += __shfl_xor(s, 4);
    s += __shfl_xor(s, 8);
    if (l == 0) {
      float alpha = 1.f / (1.f + expf(-(s + wb)));
      atomicAdd(&AB[(long long)obj * CW + sub], alpha);
      atomicAdd(&AB[(long long)obj * CW + KCAP + rel], alpha);
    }
  }
}

// ---------------- out[0:mr] = AB @ T  (mr x 2048 x 128) ----------------
__global__ void k_gemm_out(const float* __restrict__ AB, const float* __restrict__ T,
                           float* __restrict__ out, int mr) {
  __shared__ float shT[64][DIM];
  int row = blockIdx.x * 4 + (threadIdx.x >> 6);
  int cp = threadIdx.x & 63;  // col pair (float2)
  float2 acc = {0.f, 0.f};
  for (int kk = 0; kk < CW; kk += 64) {
    __syncthreads();
    for (int j = threadIdx.x; j < 64 * 32; j += 256) {
      ((float4*)shT)[j] = ((const float4*)T)[kk * 32 + j];
    }
    __syncthreads();
    const float* abr = AB + (long long)row * CW + kk;
    const float2* sh2 = (const float2*)shT;
#pragma unroll 16
    for (int k = 0; k < 64; ++k) {
      float c = abr[k];
      float2 tv = sh2[k * 64 + cp];
      acc.x += c * tv.x;
      acc.y += c * tv.y;
    }
  }
  if (row < mr) ((float2*)(out + (long long)row * DIM))[cp] = acc;
}

// ---------------- general fallback: one wave per listed edge, adds onto out ----------------
__global__ void k_fallback(const int* __restrict__ edges, const float* __restrict__ hidden,
                           const float* __restrict__ rela, const float* __restrict__ P2,
                           const float* __restrict__ C4, const float* __restrict__ Ws,
                           const float* __restrict__ w_alpha, const float* __restrict__ w_alpha_b,
                           const float* __restrict__ Wh, const int* __restrict__ left_ptr,
                           const int* __restrict__ fb_list, const int* __restrict__ fb_count,
                           float* __restrict__ out) {
  int nfb = fb_count[0];
  if (nfb == 0) return;
  int wave = (blockIdx.x * blockDim.x + threadIdx.x) >> 6;
  int nw = (gridDim.x * blockDim.x) >> 6;
  int lane = threadIdx.x & 63;
  int left = left_ptr[0];
  for (int i = wave; i < nfb; i += nw) {
    int e = fb_list[i];
    int head = edges[e * 6 + 1];
    int rel  = edges[e * 6 + 2];
    int tail = edges[e * 6 + 3];
    int sub  = edges[e * 6 + 4];
    int obj  = edges[e * 6 + 5];
    int c = ((head >= left) ? 2 : 0) | ((tail >= left) ? 1 : 0);
    float pre0 = P2[(long long)rel * DIM + lane] + C4[c * DIM + lane];
    float pre1 = P2[(long long)rel * DIM + 64 + lane] + C4[c * DIM + 64 + lane];
    for (int k = 0; k < DIM; ++k) {
      float h = hidden[(long long)sub * DIM + k];
      pre0 += h * Ws[k * DIM + lane];
      pre1 += h * Ws[k * DIM + 64 + lane];
    }
    float s = fmaxf(pre0, 0.f) * w_alpha[lane] + fmaxf(pre1, 0.f) * w_alpha[64 + lane];
    for (int d = 1; d < 64; d <<= 1) s += __shfl_xor(s, d);
    float alpha = 1.f / (1.f + expf(-(s + w_alpha_b[0])));
    float o0 = 0.f, o1 = 0.f;
    for (int k = 0; k < DIM; ++k) {
      float m = hidden[(long long)sub * DIM + k] + rela[(long long)rel * DIM + k];
      o0 += m * Wh[k * DIM + lane];
      o1 += m * Wh[k * DIM + 64 + lane];
    }
    atomicAdd(&out[(long long)obj * DIM + lane], alpha * o0);
    atomicAdd(&out[(long long)obj * DIM + 64 + lane], alpha * o1);
  }
}

extern "C" void kernel_launch(void* const* d_in, const int* in_sizes, int n_in,
                              void* d_out, int out_size, void* d_ws, size_t ws_size,
                              hipStream_t stream) {
  const float* hidden    = (const float*)d_in[0];
  const int*   edges     = (const int*)d_in[1];
  const float* kg_table  = (const float*)d_in[2];
  const float* rela      = (const float*)d_in[3];
  const float* Ws        = (const float*)d_in[4];
  const float* Wr        = (const float*)d_in[5];
  const float* Wkg_w     = (const float*)d_in[6];
  const float* Wkg_b     = (const float*)d_in[7];
  const float* w_alpha   = (const float*)d_in[8];
  const float* w_alpha_b = (const float*)d_in[9];
  const float* Wh        = (const float*)d_in[10];
  const int*   left_ptr  = (const int*)d_in[12];

  int n_node = out_size / DIM;
  int n_edge = in_sizes[1] / 6;
  int n_rel  = in_sizes[3] / DIM;
  int MR  = n_node < KCAP ? n_node : KCAP;   // dense rows (sub/obj cap)
  int NR2 = n_rel < KCAP ? n_rel : KCAP;     // dense rel cap

  char* ws = (char*)d_ws;
  size_t o = 0;
  auto alloc = [&](size_t b) { size_t r = o; o += (b + 255) & ~(size_t)255; return r; };
  float* AB     = (float*)(ws + alloc((size_t)KCAP * CW * 4));   // 8 MB
  float* SRC    = (float*)(ws + alloc((size_t)CW * DIM * 4));    // 1 MB
  float* T      = (float*)(ws + alloc((size_t)CW * DIM * 4));    // 1 MB
  float* P1     = (float*)(ws + alloc((size_t)KCAP * DIM * 4));  // 512 KB
  float* P2     = (float*)(ws + alloc((size_t)n_rel * DIM * 4));
  float* C4     = (float*)(ws + alloc(4 * DIM * 4));
  int*   fb_list  = (int*)(ws + alloc((size_t)n_edge * 4));
  int*   fb_count = (int*)(ws + alloc(4));
  float* out    = (float*)d_out;

  // zero coefficient matrix, fallback counter, and the all-zero output tail
  hipMemsetAsync(AB, 0, (size_t)KCAP * CW * 4, stream);
  hipMemsetAsync(fb_count, 0, 4, stream);
  if (n_node > MR)
    hipMemsetAsync(out + (size_t)MR * DIM, 0, ((size_t)n_node - MR) * DIM * 4, stream);

  // small precomputes
  k_src<<<256, 256, 0, stream>>>(hidden, rela, SRC, MR, NR2);
  k_proj<<<(MR * 64 + 255) / 256, 256, 0, stream>>>(hidden, Ws, P1, MR);
  k_proj<<<(n_rel * 64 + 255) / 256, 256, 0, stream>>>(rela, Wr, P2, n_rel);
  k_proj<<<(CW * 64 + 255) / 256, 256, 0, stream>>>(SRC, Wh, T, CW);
  k_c4<<<1, 128, 0, stream>>>(kg_table, Wkg_w, Wkg_b, C4);

  // per-edge alpha -> coefficient matrix
  k_edge<<<(n_edge * 16 + 255) / 256, 256, 0, stream>>>(
      edges, n_edge, P1, P2, C4, w_alpha, w_alpha_b, left_ptr,
      AB, fb_list, fb_count, MR, NR2);

  // out[0:MR] = AB @ T
  k_gemm_out<<<(MR + 3) / 4, 256, 0, stream>>>(AB, T, out, MR);

  // general-index fallback (empty for this dataset)
  k_fallback<<<64, 256, 0, stream>>>(edges, hidden, rela, P2, C4, Ws, w_alpha,
                                     w_alpha_b, Wh, left_ptr, fb_list, fb_count, out);
}

// Round 3
// 147.066 us; speedup vs baseline: 2.2474x; 1.6706x over previous
//
#include <hip/hip_runtime.h>
#include <math.h>

#define DIM   128
#define KCAP  1024   // dense cap for sub/obj indices
#define CW    2048   // AB row width: [0,KCAP)=sub coeffs, [KCAP,2*KCAP)=rel coeffs
#define KCH   256    // K-chunk for split-K output GEMM
#define NKC   (CW / KCH)   // 8 K-chunks
#define MT    32     // M-tile rows per block

// ============ fused precompute: T, P1, P2, C4 (one wave per output row) ============
__global__ void k_pre(const float* __restrict__ hidden, const float* __restrict__ rela,
                      const float* __restrict__ kg, const float* __restrict__ Ws,
                      const float* __restrict__ Wr, const float* __restrict__ Wh,
                      const float* __restrict__ Wkg, const float* __restrict__ Wkg_b,
                      float* __restrict__ P1, float* __restrict__ P2,
                      float* __restrict__ T, float* __restrict__ C4,
                      int MR, int n_rel, int NR2) {
  int wave = (blockIdx.x * blockDim.x + threadIdx.x) >> 6;
  int lane = threadIdx.x & 63;
  int nT = CW, nP1 = MR, nP2 = n_rel;
  const float* in = nullptr;
  const float* W = nullptr;
  float* outp = nullptr;
  if (wave < nT) {                       // T[r] = src(r) @ Wh
    int r = wave;
    outp = T + (long long)r * DIM;
    W = Wh;
    if (r < KCAP) { if (r < MR) in = hidden + (long long)r * DIM; }
    else { int rr = r - KCAP; if (rr < NR2) in = rela + (long long)rr * DIM; }
    if (!in) { ((float2*)outp)[lane] = make_float2(0.f, 0.f); return; }
  } else if (wave < nT + nP1) {          // P1[r] = hidden[r] @ Ws
    int r = wave - nT;
    in = hidden + (long long)r * DIM; W = Ws; outp = P1 + (long long)r * DIM;
  } else if (wave < nT + nP1 + nP2) {    // P2[r] = rela[r] @ Wr
    int r = wave - nT - nP1;
    in = rela + (long long)r * DIM; W = Wr; outp = P2 + (long long)r * DIM;
  } else if (wave < nT + nP1 + nP2 + 4) {  // C4[c] = concat(kg)...@Wkg + b
    int c = wave - nT - nP1 - nP2;
    float2 acc = ((const float2*)Wkg_b)[lane];
    const float2* W2 = (const float2*)Wkg;
    int hb = c >> 1, tb = c & 1;
#pragma unroll 4
    for (int k = 0; k < 2 * DIM; ++k) {
      float a = kg[((k < DIM) ? hb : tb) * DIM + (k & (DIM - 1))];
      float2 w = W2[k * 64 + lane];
      acc.x += a * w.x; acc.y += a * w.y;
    }
    ((float2*)(C4 + c * DIM))[lane] = acc;
    return;
  } else return;
  float2 acc = {0.f, 0.f};
  const float2* W2 = (const float2*)W;
#pragma unroll 4
  for (int k = 0; k < DIM; ++k) {
    float a = in[k];
    float2 w = W2[k * 64 + lane];
    acc.x += a * w.x; acc.y += a * w.y;
  }
  ((float2*)outp)[lane] = acc;
}

// ============ per-edge alpha -> coefficient scatter (16 lanes/edge, grid-stride) ============
__global__ void k_edge(const int* __restrict__ edges, int n_edge,
                       const float* __restrict__ P1, const float* __restrict__ P2,
                       const float* __restrict__ C4, const float* __restrict__ w_alpha,
                       const float* __restrict__ w_alpha_b, const int* __restrict__ left_ptr,
                       float* __restrict__ AB, int* __restrict__ fb_list,
                       int* __restrict__ fb_count, int mr, int nr2) {
  int tid = blockIdx.x * blockDim.x + threadIdx.x;
  int group = tid >> 4;
  int ngroups = (gridDim.x * blockDim.x) >> 4;
  int l = threadIdx.x & 15;
  int base = (threadIdx.x & 63) & ~15;
  int left = left_ptr[0];
  float wb = w_alpha_b[0];
  for (int e = group; e < n_edge; e += ngroups) {
    int v = (l < 6) ? edges[e * 6 + l] : 0;
    int head = __shfl(v, base + 1);
    int rel  = __shfl(v, base + 2);
    int tail = __shfl(v, base + 3);
    int sub  = __shfl(v, base + 4);
    int obj  = __shfl(v, base + 5);
    if (sub >= mr || obj >= mr || rel >= nr2) {
      if (l == 0) { int pos = atomicAdd(fb_count, 1); fb_list[pos] = e; }
      continue;
    }
    int c = ((head >= left) ? 2 : 0) | ((tail >= left) ? 1 : 0);
    const float4* p1 = (const float4*)(P1 + (long long)sub * DIM);
    const float4* p2 = (const float4*)(P2 + (long long)rel * DIM);
    const float4* pc = (const float4*)(C4 + c * DIM);
    const float4* wa = (const float4*)w_alpha;
    float s = 0.f;
#pragma unroll
    for (int q = 0; q < 2; ++q) {
      int idx = l * 2 + q;
      float4 a = p1[idx], b2 = p2[idx], cc = pc[idx], w4 = wa[idx];
      s += fmaxf(a.x + b2.x + cc.x, 0.f) * w4.x;
      s += fmaxf(a.y + b2.y + cc.y, 0.f) * w4.y;
      s += fmaxf(a.z + b2.z + cc.z, 0.f) * w4.z;
      s += fmaxf(a.w + b2.w + cc.w, 0.f) * w4.w;
    }
    s += __shfl_xor(s, 1);
    s += __shfl_xor(s, 2);
    s += __shfl_xor(s, 4);
    s += __shfl_xor(s, 8);
    if (l == 0) {
      float alpha = 1.f / (1.f + expf(-(s + wb)));
      atomicAdd(&AB[(long long)obj * CW + sub], alpha);
      atomicAdd(&AB[(long long)obj * CW + KCAP + rel], alpha);
    }
  }
}

// ============ split-K GEMM: part[kc][m][c] = AB[m][kc*256..]. @ T-chunk ============
// grid = (KCAP/MT) * NKC blocks; block computes a 32x128 partial over K=256.
__global__ void k_gemm2(const float* __restrict__ AB, const float* __restrict__ T,
                        float* __restrict__ part) {
  __shared__ float sh[MT][KCH + 4];   // pad 260 floats: 16B-aligned rows, conflict-free
  int mt = blockIdx.x / NKC;
  int kc = blockIdx.x % NKC;
  int m0 = mt * MT, k0 = kc * KCH;
  // stage AB tile (coalesced float4)
  for (int i = threadIdx.x; i < MT * (KCH / 4); i += 256) {
    int r = i >> 6, kq = i & 63;
    float4 v = *(const float4*)(AB + (long long)(m0 + r) * CW + k0 + kq * 4);
    *(float4*)&sh[r][kq * 4] = v;
  }
  __syncthreads();
  int cg = threadIdx.x & 31;   // col group: cols cg*4..+3
  int rg = threadIdx.x >> 5;   // row group: rows rg*4..+3
  const float4* T4 = (const float4*)T;
  float4 acc0 = {0,0,0,0}, acc1 = {0,0,0,0}, acc2 = {0,0,0,0}, acc3 = {0,0,0,0};
#pragma unroll 4
  for (int k = 0; k < KCH; ++k) {
    float4 tv = T4[(long long)(k0 + k) * (DIM / 4) + cg];
    float a0 = sh[rg * 4 + 0][k];
    float a1 = sh[rg * 4 + 1][k];
    float a2 = sh[rg * 4 + 2][k];
    float a3 = sh[rg * 4 + 3][k];
    acc0.x += a0 * tv.x; acc0.y += a0 * tv.y; acc0.z += a0 * tv.z; acc0.w += a0 * tv.w;
    acc1.x += a1 * tv.x; acc1.y += a1 * tv.y; acc1.z += a1 * tv.z; acc1.w += a1 * tv.w;
    acc2.x += a2 * tv.x; acc2.y += a2 * tv.y; acc2.z += a2 * tv.z; acc2.w += a2 * tv.w;
    acc3.x += a3 * tv.x; acc3.y += a3 * tv.y; acc3.z += a3 * tv.z; acc3.w += a3 * tv.w;
  }
  float4* p = (float4*)(part + ((long long)kc * KCAP + m0 + rg * 4) * DIM) + cg;
  p[0 * (DIM / 4)] = acc0;
  p[1 * (DIM / 4)] = acc1;
  p[2 * (DIM / 4)] = acc2;
  p[3 * (DIM / 4)] = acc3;
}

// ============ reduce partials + zero tail -> out (grid-stride) ============
__global__ void k_outfin(const float* __restrict__ part, float* __restrict__ out,
                         int n_node, int MR) {
  long long total = (long long)n_node * (DIM / 4);
  long long i = (long long)blockIdx.x * blockDim.x + threadIdx.x;
  long long stride = (long long)gridDim.x * blockDim.x;
  const float4* p4 = (const float4*)part;
  float4* o4 = (float4*)out;
  for (; i < total; i += stride) {
    long long r = i >> 5;
    int c4 = (int)(i & 31);
    float4 v = {0.f, 0.f, 0.f, 0.f};
    if (r < MR) {
#pragma unroll
      for (int kc = 0; kc < NKC; ++kc) {
        float4 t = p4[((long long)kc * KCAP + r) * (DIM / 4) + c4];
        v.x += t.x; v.y += t.y; v.z += t.z; v.w += t.w;
      }
    }
    o4[i] = v;
  }
}

// ============ general fallback: one wave per listed edge, adds onto out ============
__global__ void k_fallback(const int* __restrict__ edges, const float* __restrict__ hidden,
                           const float* __restrict__ rela, const float* __restrict__ P2,
                           const float* __restrict__ C4, const float* __restrict__ Ws,
                           const float* __restrict__ w_alpha, const float* __restrict__ w_alpha_b,
                           const float* __restrict__ Wh, const int* __restrict__ left_ptr,
                           const int* __restrict__ fb_list, const int* __restrict__ fb_count,
                           float* __restrict__ out) {
  int nfb = fb_count[0];
  if (nfb == 0) return;
  int wave = (blockIdx.x * blockDim.x + threadIdx.x) >> 6;
  int nw = (gridDim.x * blockDim.x) >> 6;
  int lane = threadIdx.x & 63;
  int left = left_ptr[0];
  for (int i = wave; i < nfb; i += nw) {
    int e = fb_list[i];
    int head = edges[e * 6 + 1];
    int rel  = edges[e * 6 + 2];
    int tail = edges[e * 6 + 3];
    int sub  = edges[e * 6 + 4];
    int obj  = edges[e * 6 + 5];
    int c = ((head >= left) ? 2 : 0) | ((tail >= left) ? 1 : 0);
    float pre0 = P2[(long long)rel * DIM + lane] + C4[c * DIM + lane];
    float pre1 = P2[(long long)rel * DIM + 64 + lane] + C4[c * DIM + 64 + lane];
    for (int k = 0; k < DIM; ++k) {
      float h = hidden[(long long)sub * DIM + k];
      pre0 += h * Ws[k * DIM + lane];
      pre1 += h * Ws[k * DIM + 64 + lane];
    }
    float s = fmaxf(pre0, 0.f) * w_alpha[lane] + fmaxf(pre1, 0.f) * w_alpha[64 + lane];
    for (int d = 1; d < 64; d <<= 1) s += __shfl_xor(s, d);
    float alpha = 1.f / (1.f + expf(-(s + w_alpha_b[0])));
    float o0 = 0.f, o1 = 0.f;
    for (int k = 0; k < DIM; ++k) {
      float m = hidden[(long long)sub * DIM + k] + rela[(long long)rel * DIM + k];
      o0 += m * Wh[k * DIM + lane];
      o1 += m * Wh[k * DIM + 64 + lane];
    }
    atomicAdd(&out[(long long)obj * DIM + lane], alpha * o0);
    atomicAdd(&out[(long long)obj * DIM + 64 + lane], alpha * o1);
  }
}

extern "C" void kernel_launch(void* const* d_in, const int* in_sizes, int n_in,
                              void* d_out, int out_size, void* d_ws, size_t ws_size,
                              hipStream_t stream) {
  const float* hidden    = (const float*)d_in[0];
  const int*   edges     = (const int*)d_in[1];
  const float* kg_table  = (const float*)d_in[2];
  const float* rela      = (const float*)d_in[3];
  const float* Ws        = (const float*)d_in[4];
  const float* Wr        = (const float*)d_in[5];
  const float* Wkg_w     = (const float*)d_in[6];
  const float* Wkg_b     = (const float*)d_in[7];
  const float* w_alpha   = (const float*)d_in[8];
  const float* w_alpha_b = (const float*)d_in[9];
  const float* Wh        = (const float*)d_in[10];
  const int*   left_ptr  = (const int*)d_in[12];

  int n_node = out_size / DIM;
  int n_edge = in_sizes[1] / 6;
  int n_rel  = in_sizes[3] / DIM;
  int MR  = n_node < KCAP ? n_node : KCAP;
  int NR2 = n_rel < KCAP ? n_rel : KCAP;

  char* ws = (char*)d_ws;
  size_t o = 0;
  auto alloc = [&](size_t b) { size_t r = o; o += (b + 255) & ~(size_t)255; return r; };
  float* AB   = (float*)(ws + alloc((size_t)KCAP * CW * 4));          // 8 MB
  float* T    = (float*)(ws + alloc((size_t)CW * DIM * 4));           // 1 MB
  float* P1   = (float*)(ws + alloc((size_t)KCAP * DIM * 4));         // 512 KB
  float* P2   = (float*)(ws + alloc((size_t)n_rel * DIM * 4));
  float* C4   = (float*)(ws + alloc(4 * DIM * 4));
  float* part = (float*)(ws + alloc((size_t)NKC * KCAP * DIM * 4));   // 4 MB
  int*   fb_list  = (int*)(ws + alloc((size_t)n_edge * 4));
  int*   fb_count = (int*)(ws + alloc(4));
  float* out  = (float*)d_out;

  hipMemsetAsync(AB, 0, (size_t)KCAP * CW * 4, stream);
  hipMemsetAsync(fb_count, 0, 4, stream);

  // fused precompute: T (2048 waves) + P1 (MR) + P2 (n_rel) + C4 (4)
  int nwaves = CW + MR + n_rel + 4;
  k_pre<<<(nwaves * 64 + 255) / 256, 256, 0, stream>>>(
      hidden, rela, kg_table, Ws, Wr, Wh, Wkg_w, Wkg_b, P1, P2, T, C4, MR, n_rel, NR2);

  // per-edge alpha -> coefficient matrix
  k_edge<<<2048, 256, 0, stream>>>(edges, n_edge, P1, P2, C4, w_alpha, w_alpha_b,
                                   left_ptr, AB, fb_list, fb_count, MR, NR2);

  // split-K GEMM into partials, then fused reduce + zero-tail + out write
  k_gemm2<<<(KCAP / MT) * NKC, 256, 0, stream>>>(AB, T, part);
  k_outfin<<<4096, 256, 0, stream>>>(part, out, n_node, MR);

  // general-index fallback (empty for this dataset)
  k_fallback<<<64, 256, 0, stream>>>(edges, hidden, rela, P2, C4, Ws, w_alpha,
                                     w_alpha_b, Wh, left_ptr, fb_list, fb_count, out);
}